// Round 1
// baseline (7302.145 us; speedup 1.0000x reference)
//
#include <hip/hip_runtime.h>
#include <hip/hip_bf16.h>

// ---------------------------------------------------------------------------
// BiLSTM T=512 B=64 D=H=512, both scans run forward (reference bug preserved).
// Strategy: fused persistent kernel; block owns 8 hidden units (32 gate cols,
// permuted contiguous); W-slice + c-state LDS-resident; bf16 MFMA 16x16x32;
// ping-pong bf16 h buffers; one custom grid barrier per timestep.
// ---------------------------------------------------------------------------

typedef short s8v __attribute__((ext_vector_type(8)));   // 8 x bf16 bits
typedef float f4v __attribute__((ext_vector_type(4)));

#define T_STEPS 512
#define BATCH   64
#define DIM     512
#define HID     512
#define KDIM    1024          // D + H
#define NB_DIR  64            // blocks per direction
#define HS      8             // hidden units per block
#define COLS    32            // 4 gates * HS
#define NBLK    (2*NB_DIR)
#define WP      1032          // LDS pitch (ushort): 1024 + 8 pad

// workspace byte offsets
#define WS_XB   0u                      // x bf16: 512*64*512*2      = 33554432
#define WS_WT   33554432u               // Wt bf16: 2*64*32*1024*2   =  8388608
#define WS_BIAS 41943040u               // bias f32: 2*2048*4        =    16384
#define WS_HBUF 41959424u               // hbuf bf16: 2*2*64*512*2   =   262144
#define WS_CNT  42221568u               // barrier counter

__device__ __forceinline__ ushort f2bf(float f) {
  unsigned u = __builtin_bit_cast(unsigned, f);
  unsigned r = u + 0x7FFFu + ((u >> 16) & 1u);   // RNE
  return (ushort)(r >> 16);
}

__global__ __launch_bounds__(256) void k_xcvt(const float* __restrict__ x,
                                              ushort* __restrict__ xb, int n8) {
  int i = blockIdx.x * 256 + threadIdx.x;
  if (i >= n8) return;
  size_t off = (size_t)i * 8;
  float4 a = *reinterpret_cast<const float4*>(x + off);
  float4 b = *reinterpret_cast<const float4*>(x + off + 4);
  s8v o;
  o[0] = (short)f2bf(a.x); o[1] = (short)f2bf(a.y);
  o[2] = (short)f2bf(a.z); o[3] = (short)f2bf(a.w);
  o[4] = (short)f2bf(b.x); o[5] = (short)f2bf(b.y);
  o[6] = (short)f2bf(b.z); o[7] = (short)f2bf(b.w);
  *reinterpret_cast<s8v*>(xb + off) = o;
}

// Build permuted W^T (bf16): Wt[d][nb][p][k], p = gate*8+u, k<512 from Wih,
// k>=512 from Whh. One thread per (d, col); k-contiguous 16B stores.
__global__ __launch_bounds__(256) void k_wtprep(const float* __restrict__ WihF,
                                                const float* __restrict__ WhhF,
                                                const float* __restrict__ WihB,
                                                const float* __restrict__ WhhB,
                                                ushort* __restrict__ Wt) {
  int g = blockIdx.x * 256 + threadIdx.x;       // 0..4095
  int d = g >> 11, col = g & 2047;
  const float* Wih = d ? WihB : WihF;
  const float* Whh = d ? WhhB : WhhF;
  int gate = col >> 9, j = col & 511;
  int nb = j >> 3, u = j & 7, p = (gate << 3) | u;
  ushort* dst = Wt + (((size_t)(d * NB_DIR + nb) * COLS + p) << 10);
  for (int k0 = 0; k0 < KDIM; k0 += 8) {
    s8v o;
#pragma unroll
    for (int i = 0; i < 8; ++i) {
      int k = k0 + i;
      float v = (k < 512) ? Wih[k * 2048 + col] : Whh[(k - 512) * 2048 + col];
      o[i] = (short)f2bf(v);
    }
    *reinterpret_cast<s8v*>(dst + k0) = o;
  }
}

__global__ __launch_bounds__(256) void k_init(const float* __restrict__ bihF,
                                              const float* __restrict__ bhhF,
                                              const float* __restrict__ bihB,
                                              const float* __restrict__ bhhB,
                                              float* __restrict__ bias,
                                              unsigned* __restrict__ hbuf_u32,
                                              unsigned* __restrict__ cnt) {
  int g = blockIdx.x * 256 + threadIdx.x;
  if (g < 65536) hbuf_u32[g] = 0u;              // zero both h ping-pong bufs
  if (g < 2048) {
    bias[g]        = bihF[g] + bhhF[g];
    bias[2048 + g] = bihB[g] + bhhB[g];
  }
  if (g == 0) *cnt = 0u;
}

__global__ __launch_bounds__(256, 1) void k_lstm(const ushort* __restrict__ xb,
                                                 const ushort* __restrict__ Wt,
                                                 const float* __restrict__ bias,
                                                 ushort* hbuf,
                                                 float* __restrict__ out,
                                                 unsigned* cnt) {
  __shared__ ushort Wlds[COLS][WP];             // 66 KB, 2-way bank alias only
  __shared__ float gates[BATCH][COLS + 1];      // 8.4 KB
  __shared__ float cst[BATCH][HS];              // 2 KB, persistent c state
  __shared__ float biasl[COLS];

  const int tid  = threadIdx.x;
  const int dir  = blockIdx.x & 1;
  const int nb   = blockIdx.x >> 1;
  const int lane = tid & 63;
  const int w    = tid >> 6;                    // wave id == m-tile
  const int j0   = nb * HS;

  // stage W slice (global -> LDS), once
  const ushort* wsrc = Wt + ((size_t)(dir * NB_DIR + nb) << 15);
  for (int v = tid; v < COLS * 128; v += 256) {
    int p = v >> 7, kk = (v & 127) << 3;
    *reinterpret_cast<s8v*>(&Wlds[p][kk]) =
        *reinterpret_cast<const s8v*>(wsrc + (p << 10) + kk);
  }
  if (tid < COLS)
    biasl[tid] = bias[dir * 2048 + ((tid >> 3) << 9) + j0 + (tid & 7)];
  for (int v = tid; v < BATCH * HS; v += 256) cst[v >> 3][v & 7] = 0.f;
  __syncthreads();

  const int arow = (w << 4) + (lane & 15);      // batch row for A frags
  const int kgrp = (lane >> 4) << 3;            // 0,8,16,24
  const int pc   = lane & 15;                   // frag col within n-tile

  float* outH  = out;                            // [512][64][1024]
  float* outHn = out + (size_t)33554432;
  float* outCn = outHn + 65536;

  for (int t = 0; t < T_STEPS; ++t) {
    f4v acc0 = {0.f, 0.f, 0.f, 0.f}, acc1 = {0.f, 0.f, 0.f, 0.f};
    const ushort* xa = xb + (((size_t)t * BATCH + arow) << 9) + kgrp;
    const ushort* ha = hbuf +
        ((size_t)(((dir << 1) | ((t + 1) & 1)) * BATCH + arow) << 9) + kgrp;
#pragma unroll
    for (int kb = 0; kb < 16; ++kb) {           // x part, k = 0..511
      s8v a  = *reinterpret_cast<const s8v*>(xa + (kb << 5));
      s8v b0 = *reinterpret_cast<const s8v*>(&Wlds[pc][(kb << 5) + kgrp]);
      s8v b1 = *reinterpret_cast<const s8v*>(&Wlds[16 + pc][(kb << 5) + kgrp]);
      acc0 = __builtin_amdgcn_mfma_f32_16x16x32_bf16(a, b0, acc0, 0, 0, 0);
      acc1 = __builtin_amdgcn_mfma_f32_16x16x32_bf16(a, b1, acc1, 0, 0, 0);
    }
#pragma unroll
    for (int kb = 0; kb < 16; ++kb) {           // h part, k = 512..1023
      s8v a  = *reinterpret_cast<const s8v*>(ha + (kb << 5));
      s8v b0 = *reinterpret_cast<const s8v*>(&Wlds[pc][512 + (kb << 5) + kgrp]);
      s8v b1 = *reinterpret_cast<const s8v*>(&Wlds[16 + pc][512 + (kb << 5) + kgrp]);
      acc0 = __builtin_amdgcn_mfma_f32_16x16x32_bf16(a, b0, acc0, 0, 0, 0);
      acc1 = __builtin_amdgcn_mfma_f32_16x16x32_bf16(a, b1, acc1, 0, 0, 0);
    }
    // D layout: col = lane&15, row = (lane>>4)*4 + reg  [m89-verified]
    {
      int r0 = (w << 4) + ((lane >> 4) << 2);
#pragma unroll
      for (int r = 0; r < 4; ++r) {
        gates[r0 + r][pc]      = acc0[r];
        gates[r0 + r][16 + pc] = acc1[r];
      }
    }
    __syncthreads();
    for (int q = tid; q < BATCH * HS; q += 256) {
      int b = q >> 3, u = q & 7;
      float ig = gates[b][u]      + biasl[u];
      float fg = gates[b][8 + u]  + biasl[8 + u];
      float gg = gates[b][16 + u] + biasl[16 + u];
      float og = gates[b][24 + u] + biasl[24 + u];
      float cp = cst[b][u];
      float si = 1.f / (1.f + __expf(-ig));
      float sf = 1.f / (1.f + __expf(-fg));
      float so = 1.f / (1.f + __expf(-og));
      float tg = 1.f - 2.f / (__expf(2.f * gg) + 1.f);
      float c  = sf * cp + si * tg;
      float tc = 1.f - 2.f / (__expf(2.f * c) + 1.f);
      float h  = so * tc;
      cst[b][u] = c;
      int jg = j0 + u;
      size_t oc = ((size_t)b << 10) + (dir << 9) + jg;
      outH[((size_t)t << 16) + oc] = h;
      hbuf[((size_t)(((dir << 1) | (t & 1)) * BATCH + b) << 9) + jg] = f2bf(h);
      if (t == T_STEPS - 1) { outHn[oc] = h; outCn[oc] = c; }
    }
    if (t < T_STEPS - 1) {
      __syncthreads();                          // drains hbuf stores (vmcnt 0)
      if (tid == 0) {
        __threadfence();                        // L2 writeback, device scope
        __hip_atomic_fetch_add(cnt, 1u, __ATOMIC_RELEASE,
                               __HIP_MEMORY_SCOPE_AGENT);
        unsigned target = (unsigned)NBLK * (unsigned)(t + 1);
        while (__hip_atomic_load(cnt, __ATOMIC_RELAXED,
                                 __HIP_MEMORY_SCOPE_AGENT) < target)
          __builtin_amdgcn_s_sleep(1);
        __threadfence();                        // acquire: invalidate L1/L2
      }
      __syncthreads();
    }
  }
}

extern "C" void kernel_launch(void* const* d_in, const int* in_sizes, int n_in,
                              void* d_out, int out_size, void* d_ws, size_t ws_size,
                              hipStream_t stream) {
  const float* x    = (const float*)d_in[0];
  const float* WihF = (const float*)d_in[1];
  const float* WhhF = (const float*)d_in[2];
  const float* bihF = (const float*)d_in[3];
  const float* bhhF = (const float*)d_in[4];
  const float* WihB = (const float*)d_in[5];
  const float* WhhB = (const float*)d_in[6];
  const float* bihB = (const float*)d_in[7];
  const float* bhhB = (const float*)d_in[8];

  char* ws = (char*)d_ws;
  ushort*   xb   = (ushort*)(ws + WS_XB);
  ushort*   Wt   = (ushort*)(ws + WS_WT);
  float*    bias = (float*)(ws + WS_BIAS);
  ushort*   hbuf = (ushort*)(ws + WS_HBUF);
  unsigned* cnt  = (unsigned*)(ws + WS_CNT);

  k_xcvt<<<8192, 256, 0, stream>>>(x, xb, 2097152);
  k_wtprep<<<16, 256, 0, stream>>>(WihF, WhhF, WihB, WhhB, Wt);
  k_init<<<256, 256, 0, stream>>>(bihF, bhhF, bihB, bhhB, bias,
                                  (unsigned*)hbuf, cnt);
  k_lstm<<<NBLK, 256, 0, stream>>>(xb, Wt, bias, hbuf, (float*)d_out, cnt);
}